// Round 6
// baseline (480.101 us; speedup 1.0000x reference)
//
#include <hip/hip_runtime.h>
#include <hip/hip_bf16.h>
#include <cmath>

// Problem constants
#define B_    4
#define T_    2048
#define DIM_  1024
#define H_    16
#define NOPE_ 128
#define ROPE_ 64
#define VDIM_ 128
#define KVR_  512
#define QKD_  192          // NOPE + ROPE
#define NTOK  (B_ * T_)    // 8192

static constexpr float SCALE2_ = 0.07216878364870322f * 1.4426950408889634f; // 1/sqrt(192) * log2(e)

typedef __attribute__((ext_vector_type(8))) unsigned short ushort8_t;
typedef __bf16 v8bf __attribute__((ext_vector_type(8)));
typedef float  v4f  __attribute__((ext_vector_type(4)));
typedef unsigned int v4u __attribute__((ext_vector_type(4)));

__device__ __forceinline__ float bf2f(unsigned short u) {
    return __uint_as_float(((unsigned int)u) << 16);
}
__device__ __forceinline__ unsigned short f2bf(float f) {
    unsigned int u = __float_as_uint(f);
    u += 0x7FFFu + ((u >> 16) & 1u);
    return (unsigned short)(u >> 16);
}
// HW bf16 convert: fptrunc f32->bf16 lowers to v_cvt_pk_bf16_f32 (1 inst, RTNE)
__device__ __forceinline__ unsigned short f2bf_hw(float f) {
    return __builtin_bit_cast(unsigned short, (__bf16)f);
}
// packed pair: low16 = bf16(lo), high16 = bf16(hi) — single instruction
__device__ __forceinline__ unsigned int cvt_pk_bf16(float lo, float hi) {
    unsigned int r;
    asm("v_cvt_pk_bf16_f32 %0, %1, %2" : "=v"(r) : "v"(lo), "v"(hi));
    return r;
}
__device__ __forceinline__ void store1(float* p, float v)          { *p = v; }
__device__ __forceinline__ void store1(__hip_bfloat16* p, float v) { *p = __float2bfloat16(v); }

// RAW v_exp_f32 (D = 2^S0) — 1 instruction (r10 lesson: exp2f is OCML, slow).
__device__ __forceinline__ float exp2_hw(float x) {
    return __builtin_amdgcn_exp2f(x);
}

// async global->LDS, 16B per lane. LDS dest = wave-uniform base + lane*16.
__device__ __forceinline__ void load_lds16(const void* g, void* l) {
    __builtin_amdgcn_global_load_lds(
        (const __attribute__((address_space(1))) void*)g,
        (__attribute__((address_space(3))) void*)l, 16, 0, 0);
}

__device__ __forceinline__ void cvt4(const float* s, __hip_bfloat16* d, int q4) {
    const int i = q4 * 4;
    const float4 v = *(const float4*)(s + i);
    ushort4 o;
    o.x = f2bf(v.x); o.y = f2bf(v.y); o.z = f2bf(v.z); o.w = f2bf(v.w);
    *(ushort4*)((unsigned short*)d + i) = o;
}

// ---------------------------------------------------------------------------
// ONE kernel for all fp32->bf16 conversions.
// ---------------------------------------------------------------------------
#define X4_   (NTOK*1024/4)
#define Q4_   (3072*1024/4)
#define KB4_  (4096*512/4)
#define O4_   (1024*2048/4)
#define A4_   (640*1024/4)
#define CVT_TOTAL (X4_ + Q4_ + KB4_ + O4_ + A4_)

__global__ __launch_bounds__(256) void cvt_all(
    const float* __restrict__ x,    const float* __restrict__ wq,
    const float* __restrict__ wkvb, const float* __restrict__ wo,
    const float* __restrict__ wkva, const float* __restrict__ wkva_bias,
    __hip_bfloat16* __restrict__ xb,    __hip_bfloat16* __restrict__ wqb,
    __hip_bfloat16* __restrict__ wkvbb, __hip_bfloat16* __restrict__ wob,
    __hip_bfloat16* __restrict__ wkvab, float* __restrict__ bias_pad)
{
    int idx = blockIdx.x * 256 + threadIdx.x;
    if (idx < X4_) { cvt4(x, xb, idx); return; }
    idx -= X4_;
    if (idx < Q4_) { cvt4(wq, wqb, idx); return; }
    idx -= Q4_;
    if (idx < KB4_) { cvt4(wkvb, wkvbb, idx); return; }
    idx -= KB4_;
    if (idx < O4_) { cvt4(wo, wob, idx); return; }
    idx -= O4_;
    if (idx < A4_) {
        const int i = idx * 4;
        ushort4 o;
        if (i < 576 * 1024) {
            const float4 v = *(const float4*)(wkva + i);
            o.x = f2bf(v.x); o.y = f2bf(v.y); o.z = f2bf(v.z); o.w = f2bf(v.w);
        } else {
            o.x = o.y = o.z = o.w = 0;
        }
        *(ushort4*)((unsigned short*)wkvab + i) = o;
        if (idx < 640) bias_pad[idx] = (idx < 576) ? wkva_bias[idx] : 0.0f;
    }
}

// ---------------------------------------------------------------------------
// MFMA GEMM: C[m][n] = sum_k A[m][k]*W[n][k] + bias[n].
// T1 XCD swizzle: dispatch is x-fast round-robin over 8 XCDs, so blocks
// sharing a B-panel (same x) landed on different XCDs -> B thrashed private
// L2s. Bijective remap (nwg%8==0 for all our grids) gives each XCD a
// contiguous x-stripe: B working set per XCD <= ~1MB (L2-resident).
// EPI=0: plain store to C.  EPI=1 (kv_b): fragment-ordered kvf via LDS bounce.
// ---------------------------------------------------------------------------
template <typename CT, int EPI>
__global__ __launch_bounds__(256) void gemm_mfma(
    const __hip_bfloat16* __restrict__ A, int lda,
    const __hip_bfloat16* __restrict__ W, int ldw,
    const float* __restrict__ bias,
    CT* __restrict__ C, int ldc, int K,
    unsigned short* __restrict__ kvf)
{
    __shared__ unsigned short smem[2 * 128 * 32];   // 16 KB: A|B tiles, then frag block
    unsigned short* A_s = smem;
    unsigned short* B_s = smem + 128 * 32;

    const int tid  = threadIdx.x;
    const int ln   = tid & 63;
    const int wv   = tid >> 6;
    const int l15  = ln & 15;
    const int quad = ln >> 4;
    const int wm   = wv & 1, wn = wv >> 1;

    // XCD-stripe swizzle (x-major work enumeration)
    const int nwx = (int)gridDim.x, nwy = (int)gridDim.y;
    const int flat = (int)blockIdx.x + nwx * (int)blockIdx.y;
    const int cpx = (nwx * nwy) >> 3;               // nwg % 8 == 0
    const int swz = (flat & 7) * cpx + (flat >> 3);
    const int n0 = (swz / nwy) * 128, m0 = (swz % nwy) * 128;

    v4f acc[4][4] = {};

    for (int k0 = 0; k0 < K; k0 += 32) {
        __syncthreads();
        #pragma unroll
        for (int it = 0; it < 2; ++it) {
            const int idx = it * 256 + wv * 64;
            const int li  = idx + ln;
            const int row = li >> 2, ch = li & 3;
            load_lds16(A + (size_t)(m0 + row) * lda + k0 + ch * 8, &A_s[idx * 8]);
            load_lds16(W + (size_t)(n0 + row) * ldw + k0 + ch * 8, &B_s[idx * 8]);
        }
        __syncthreads();

        v8bf af[4], bf_[4];
        #pragma unroll
        for (int i = 0; i < 4; ++i) {
            af[i]  = *(const v8bf*)&A_s[(wm * 64 + i * 16 + l15) * 32 + quad * 8];
            bf_[i] = *(const v8bf*)&B_s[(wn * 64 + i * 16 + l15) * 32 + quad * 8];
        }
        #pragma unroll
        for (int i = 0; i < 4; ++i)
            #pragma unroll
            for (int j = 0; j < 4; ++j)
                acc[i][j] = __builtin_amdgcn_mfma_f32_16x16x32_bf16(
                                af[i], bf_[j], acc[i][j], 0, 0, 0);
    }

    if (EPI == 0) {
        #pragma unroll
        for (int i = 0; i < 4; ++i) {
            const int mrow = m0 + wm * 64 + i * 16 + quad * 4;
            #pragma unroll
            for (int j = 0; j < 4; ++j) {
                const int ncol = n0 + wn * 64 + j * 16 + l15;
                const float bb = bias[ncol];
                #pragma unroll
                for (int r = 0; r < 4; ++r)
                    store1(C + (size_t)(mrow + r) * ldc + ncol, acc[i][j][r] + bb);
            }
        }
    } else {
        const int head = n0 >> 8;
        const bool is_v = (n0 & 128) != 0;
        __syncthreads();   // main-loop LDS reads complete before overwrite
        #pragma unroll
        for (int p = 0; p < 2; ++p) {          // p = local ktile = wm
            if (p) __syncthreads();            // pass-0 copyout done
            if (wm == p) {
                #pragma unroll
                for (int i = 0; i < 4; ++i) {
                    #pragma unroll
                    for (int j = 0; j < 4; ++j) {
                        const int ncl = wn * 64 + j * 16 + l15;   // dim 0..127
                        const float bb = bias[n0 + ncl];
                        #pragma unroll
                        for (int r = 0; r < 4; ++r) {
                            const unsigned short v = f2bf(acc[i][j][r] + bb);
                            const int lnf = quad * 4 + r;          // tok%16
                            int off;
                            if (!is_v) {
                                const int s = ncl >> 5, qf = (ncl >> 3) & 3, e = ncl & 7;
                                off = (s * 4 + i) * 512 + (qf * 16 + lnf) * 8 + e;
                            } else {
                                const int nt = ncl >> 4, lnv = ncl & 15;
                                const int jj = i * 16 + lnf;       // tok%64
                                const int s2 = jj >> 5, qv = (jj >> 3) & 3, ev = jj & 7;
                                off = (nt * 2 + s2) * 512 + (qv * 16 + lnv) * 8 + ev;
                            }
                            smem[off] = v;
                        }
                    }
                }
            }
            __syncthreads();
            // coalesced copy: 16 KB fragment block -> kvf
            const size_t GT = (size_t)(m0 >> 6) + p;
            unsigned short* dst = kvf + ((GT * 16 + head) << 14) + (is_v ? 16 * 512 : 0);
            #pragma unroll
            for (int it = 0; it < 4; ++it) {
                const int u = (tid + it * 256) * 8;
                *(ushort8_t*)(dst + u) = *(const ushort8_t*)&smem[u];
            }
        }
    }
}

// ---------------------------------------------------------------------------
// Fused q-proj + kva-proj (same A operand, K=1024): one launch, branch on bx.
// Same T1 XCD swizzle (nwg = 29*64 = 1856, %8==0).
// ---------------------------------------------------------------------------
__global__ __launch_bounds__(256) void gemm_qkva(
    const __hip_bfloat16* __restrict__ A,
    const __hip_bfloat16* __restrict__ Wq, const float* __restrict__ biasq,
    __hip_bfloat16* __restrict__ Cq,
    const __hip_bfloat16* __restrict__ Wa, const float* __restrict__ biasa,
    __hip_bfloat16* __restrict__ Ca)
{
    __shared__ unsigned short smem[2 * 128 * 32];
    unsigned short* A_s = smem;
    unsigned short* B_s = smem + 128 * 32;

    const int flat = (int)blockIdx.x + 29 * (int)blockIdx.y;
    const int swz  = (flat & 7) * (1856 >> 3) + (flat >> 3);
    const int xw   = swz / 64, yw = swz % 64;

    const bool is_q = xw < 24;
    const __hip_bfloat16* W = is_q ? Wq : Wa;
    const float* bias       = is_q ? biasq : biasa;
    __hip_bfloat16* C       = is_q ? Cq : Ca;
    const int ldc = is_q ? 3072 : 640;
    const int n0  = (is_q ? xw : (xw - 24)) * 128;
    const int m0  = yw * 128;

    const int tid  = threadIdx.x;
    const int ln   = tid & 63;
    const int wv   = tid >> 6;
    const int l15  = ln & 15;
    const int quad = ln >> 4;
    const int wm   = wv & 1, wn = wv >> 1;

    v4f acc[4][4] = {};

    for (int k0 = 0; k0 < 1024; k0 += 32) {
        __syncthreads();
        #pragma unroll
        for (int it = 0; it < 2; ++it) {
            const int idx = it * 256 + wv * 64;
            const int li  = idx + ln;
            const int row = li >> 2, ch = li & 3;
            load_lds16(A + (size_t)(m0 + row) * 1024 + k0 + ch * 8, &A_s[idx * 8]);
            load_lds16(W + (size_t)(n0 + row) * 1024 + k0 + ch * 8, &B_s[idx * 8]);
        }
        __syncthreads();

        v8bf af[4], bf_[4];
        #pragma unroll
        for (int i = 0; i < 4; ++i) {
            af[i]  = *(const v8bf*)&A_s[(wm * 64 + i * 16 + l15) * 32 + quad * 8];
            bf_[i] = *(const v8bf*)&B_s[(wn * 64 + i * 16 + l15) * 32 + quad * 8];
        }
        #pragma unroll
        for (int i = 0; i < 4; ++i)
            #pragma unroll
            for (int j = 0; j < 4; ++j)
                acc[i][j] = __builtin_amdgcn_mfma_f32_16x16x32_bf16(
                                af[i], bf_[j], acc[i][j], 0, 0, 0);
    }

    #pragma unroll
    for (int i = 0; i < 4; ++i) {
        const int mrow = m0 + wm * 64 + i * 16 + quad * 4;
        #pragma unroll
        for (int j = 0; j < 4; ++j) {
            const int ncol = n0 + wn * 64 + j * 16 + l15;
            const float bb = bias[ncol];
            #pragma unroll
            for (int r = 0; r < 4; ++r)
                C[(size_t)(mrow + r) * ldc + ncol] = __float2bfloat16(acc[i][j][r] + bb);
        }
    }
}

// ---------------------------------------------------------------------------
// RMS-norm kv_a[:,0:512] -> kvn bf16; RoPE kv_a[:,512:576] -> kr bf16.
// ---------------------------------------------------------------------------
__global__ __launch_bounds__(256) void rmsnorm_ropek(
    const __hip_bfloat16* __restrict__ kva,
    __hip_bfloat16* __restrict__ kvn,
    __hip_bfloat16* __restrict__ kr,
    const float* __restrict__ cs,
    const float* __restrict__ sn)
{
    const int tok = blockIdx.x;
    const int tid = threadIdx.x;
    const __hip_bfloat16* row = kva + (size_t)tok * 640;

    const float x0 = __bfloat162float(row[tid]);
    const float x1 = __bfloat162float(row[tid + 256]);
    float ss = x0*x0 + x1*x1;
    #pragma unroll
    for (int off = 32; off >= 1; off >>= 1)
        ss += __shfl_down(ss, off);

    __shared__ float red[4];
    __shared__ float scale_sh;
    if ((tid & 63) == 0) red[tid >> 6] = ss;
    __syncthreads();
    if (tid == 0) {
        const float tot = red[0] + red[1] + red[2] + red[3];
        scale_sh = rsqrtf(tot * (1.0f/512.0f) + 1e-6f);
    }
    __syncthreads();
    const float sc = scale_sh;
    kvn[(size_t)tok*512 + tid]       = __float2bfloat16(x0 * sc);
    kvn[(size_t)tok*512 + tid + 256] = __float2bfloat16(x1 * sc);

    if (tid < 32) {
        const int t = tok & (T_ - 1);
        const float c = cs[t*32 + tid];
        const float s = sn[t*32 + tid];
        const float xr = __bfloat162float(row[KVR_ + 2*tid]);
        const float xi = __bfloat162float(row[KVR_ + 2*tid + 1]);
        kr[(size_t)tok*64 + 2*tid]     = __float2bfloat16(xr * c - xi * s);
        kr[(size_t)tok*64 + 2*tid + 1] = __float2bfloat16(xr * s + xi * c);
    }
}

// ---------------------------------------------------------------------------
// MFMA flash attention, BQ=256 / BK=64, 8 waves, two q-strips per wave.
// SWAPPED QK^T: S^T = mfma(K, Q); lane-local softmax; in-register P frags.
//
// DOUBLE-BUFFERED KVf (this round): LDS 2x40KB = 80KB/block; 2 blocks/CU =
// 163840 B = exactly the 160 KiB pool. One barrier per K-tile (was two), and
// the tile-(k+1) LDS write moves off the critical path: it issues after this
// iter's compute and is drained by the next barrier's implicit waitcnt.
// Readers of the alt buffer finished before this iter's barrier -> safe.
// R5 counters: occupancy 21.8% = long block of each pair runs alone most of
// the wall; its serial chain (stage-write+2 barriers) is what dbuf cuts.
// ---------------------------------------------------------------------------
__device__ __forceinline__ void attn_stage_regs(
    v8bf* R,
    const unsigned short* __restrict__ kvf,
    const __hip_bfloat16* __restrict__ kr,
    size_t tokb, int j0, int h, int wv, int lane, int tid)
{
    const size_t GT = (tokb + j0) >> 6;
    const unsigned short* base = kvf + ((GT * 16 + h) << 14);
    #pragma unroll
    for (int i = 0; i < 4; ++i)
        R[i] = *(const v8bf*)(base + ((wv * 4 + i) << 9) + lane * 8);
    // kr: thread (j=tid>>3, dch=tid&7) -> 16B coalesced
    const int j = tid >> 3, dch = tid & 7;
    R[4] = *(const v8bf*)((const unsigned short*)kr + (tokb + j0 + j) * 64 + dch * 8);
}

__global__ __launch_bounds__(512, 2) void attn_mfma(
    const __hip_bfloat16* __restrict__ q,
    const unsigned short* __restrict__ kvf,
    const __hip_bfloat16* __restrict__ kr,
    const float* __restrict__ cs,
    const float* __restrict__ sn,
    __hip_bfloat16* __restrict__ att)
{
    __shared__ unsigned short KVf[2][40 * 512];     // 80 KB, double-buffered

    const int tid  = threadIdx.x;
    const int lane = tid & 63;
    const int ln   = tid & 15;
    const int quad = (tid >> 4) & 3;
    const int wv   = tid >> 6;                      // 0..7
    const int hf   = quad >> 1;                     // 1 iff lane >= 32
    const int p2   = quad & 1;

    // ---- balanced (qt,h,b) mapping from flattened dispatch id ----
    const int bid  = (int)(blockIdx.x + 8u * blockIdx.y + 128u * blockIdx.z);
    const int half = bid >> 8;          // 0 or 1
    const int id2  = bid & 255;
    const int pr   = id2 & 3;           // complementary pair id (0..3)
    const int h    = (id2 >> 2) & 15;
    const int b    = id2 >> 6;
    const int qt   = half ? pr : (7 - pr);

    const int q0 = qt * 256;
    const size_t tokb = (size_t)b * T_;

    // ---- Q fragments (B operand), fused RoPE + base2 scale ----
    v8bf qf[2][6];
    #pragma unroll
    for (int st = 0; st < 2; ++st) {
        const int trow = q0 + st*128 + wv*16 + ln;
        const __hip_bfloat16* qrow =
            q + (tokb + trow) * (size_t)(H_*QKD_) + h*QKD_;
        #pragma unroll
        for (int s = 0; s < 6; ++s) {
            ushort8_t raw = *(const ushort8_t*)(qrow + s*32 + quad*8);
            ushort8_t o;
            if (s < 4) {
                #pragma unroll
                for (int i = 0; i < 8; ++i)
                    o[i] = f2bf_hw(bf2f(raw[i]) * SCALE2_);
            } else {
                #pragma unroll
                for (int pp2 = 0; pp2 < 4; ++pp2) {
                    const int fi = (s-4)*16 + quad*4 + pp2;
                    const float c  = cs[trow*32 + fi];
                    const float sv = sn[trow*32 + fi];
                    const float xr = bf2f(raw[pp2*2]);
                    const float xi = bf2f(raw[pp2*2+1]);
                    o[pp2*2]   = f2bf_hw((xr*c - xi*sv) * SCALE2_);
                    o[pp2*2+1] = f2bf_hw((xr*sv + xi*c) * SCALE2_);
                }
            }
            qf[st][s] = __builtin_bit_cast(v8bf, o);
        }
    }

    v4f O[2][8];
    #pragma unroll
    for (int st = 0; st < 2; ++st)
        #pragma unroll
        for (int nt = 0; nt < 8; ++nt) O[st][nt] = (v4f){0.f, 0.f, 0.f, 0.f};
    float m_r[2] = {-1e30f, -1e30f};
    float l_r[2] = {0.0f, 0.0f};

    const int qmin0 = q0 + wv*16;
    const int qmin1 = q0 + 128 + wv*16;
    const int nkt = (q0 + 256) >> 6;

    // LDS slot base for this wave's 4 kvf fragments (kn->0..15, V->24..39)
    const int slot0 = (wv < 4) ? (wv * 4) : (wv * 4 + 8);
    // kr LDS target for this thread
    const int krj = tid >> 3, krd = tid & 7;
    const int krfrag = 16 + (krd >> 2) * 4 + (krj >> 4);
    const int kroff  = krfrag * 512 + ((krd & 3) * 16 + (krj & 15)) * 8;

    // prefetch tile 0 and write it into buffer 0 (pre-loop)
    v8bf R[5];
    attn_stage_regs(R, kvf, kr, tokb, 0, h, wv, lane, tid);
    {
        unsigned short* Kw = KVf[0];
        #pragma unroll
        for (int i = 0; i < 4; ++i)
            *(v8bf*)&Kw[(slot0 + i) * 512 + lane * 8] = R[i];
        *(v8bf*)&Kw[kroff] = R[4];
    }

    for (int kt = 0; kt < nkt; ++kt) {
        const int j0 = kt << 6;
        const int cur = kt & 1;
        const unsigned short* Kb = KVf[cur];

        __syncthreads();   // buf[cur] visible; buf[cur^1] free (readers done)

        if (kt + 1 < nkt)
            attn_stage_regs(R, kvf, kr, tokb, j0 + 64, h, wv, lane, tid);

        const bool act0 = (j0 <= qmin0 + 15);   // wave-uniform
        const bool act1 = (j0 <= qmin1 + 15);

        if (act1) {
            // ---- S^T = K Q^T : lane&15 = q-row, kpos = j0 + t*16 + quad*4 + r ----
            v4f S[2][4];
            #pragma unroll
            for (int st = 0; st < 2; ++st)
                #pragma unroll
                for (int t = 0; t < 4; ++t) S[st][t] = (v4f){0.f, 0.f, 0.f, 0.f};
            __builtin_amdgcn_s_setprio(1);
            if (act0) {
                #pragma unroll
                for (int s = 0; s < 6; ++s)
                    #pragma unroll
                    for (int t = 0; t < 4; ++t) {
                        const v8bf kb = *(const v8bf*)&Kb[(s*4 + t)*512 + lane*8];
                        S[0][t] = __builtin_amdgcn_mfma_f32_16x16x32_bf16(kb, qf[0][s], S[0][t], 0, 0, 0);
                        S[1][t] = __builtin_amdgcn_mfma_f32_16x16x32_bf16(kb, qf[1][s], S[1][t], 0, 0, 0);
                    }
            } else {
                #pragma unroll
                for (int s = 0; s < 6; ++s)
                    #pragma unroll
                    for (int t = 0; t < 4; ++t) {
                        const v8bf kb = *(const v8bf*)&Kb[(s*4 + t)*512 + lane*8];
                        S[1][t] = __builtin_amdgcn_mfma_f32_16x16x32_bf16(kb, qf[1][s], S[1][t], 0, 0, 0);
                    }
            }
            __builtin_amdgcn_s_setprio(0);

            // ---- lane-local online softmax + in-register P fragment build ----
            v8bf pfrag[2][2];
            #pragma unroll
            for (int st = 0; st < 2; ++st) {
                if (st == 0 && !act0) continue;
                const int qmin = (st == 0) ? qmin0 : qmin1;
                const int qrow = qmin + ln;             // this lane's absolute q
                if (j0 + 63 > qmin) {
                    #pragma unroll
                    for (int t = 0; t < 4; ++t) {
                        const int kbase = j0 + t*16 + quad*4;
                        #pragma unroll
                        for (int r = 0; r < 4; ++r)
                            if (kbase + r > qrow) S[st][t][r] = -1e30f;
                    }
                }
                // row max: lane-local tree + 2 cross-quad shfls
                float mx = S[st][0][0];
                #pragma unroll
                for (int t = 0; t < 4; ++t)
                    #pragma unroll
                    for (int r = 0; r < 4; ++r)
                        if (t || r) mx = fmaxf(mx, S[st][t][r]);
                mx = fmaxf(mx, __shfl_xor(mx, 16));
                mx = fmaxf(mx, __shfl_xor(mx, 32));
                const bool need = mx > m_r[st] + 8.0f;  // defer-max THR=8 (base-2)
                if (__any((int)need)) {
                    const float mn = fmaxf(m_r[st], mx);
                    const float alpha = exp2_hw(m_r[st] - mn);
                    m_r[st] = mn;
                    l_r[st] *= alpha;
                    #pragma unroll
                    for (int nt = 0; nt < 8; ++nt)
                        O[st][nt] *= alpha;
                }
                // exp + lane-local sum + 2 shfls
                float rs = 0.0f;
                #pragma unroll
                for (int t = 0; t < 4; ++t)
                    #pragma unroll
                    for (int r = 0; r < 4; ++r) {
                        const float pp = exp2_hw(S[st][t][r] - m_r[st]);
                        S[st][t][r] = pp;
                        rs += pp;
                    }
                rs += __shfl_xor(rs, 16);
                rs += __shfl_xor(rs, 32);
                l_r[st] += rs;
                // pack P pairs: pk[t][i] = (kpos t*16+quad*4+2i, +1)
                unsigned int pk[4][2];
                #pragma unroll
                for (int t = 0; t < 4; ++t)
                    #pragma unroll
                    for (int i = 0; i < 2; ++i)
                        pk[t][i] = cvt_pk_bf16(S[st][t][2*i], S[st][t][2*i+1]);
                // quad exchange -> B fragments (lane=q, elems tok = s2*32+quad*8+e)
                #pragma unroll
                for (int s2 = 0; s2 < 2; ++s2) {
                    const unsigned int A0 = pk[2*s2][0],   A1 = pk[2*s2][1];
                    const unsigned int B0 = pk[2*s2+1][0], B1 = pk[2*s2+1][1];
                    const unsigned int sB0 = __shfl_xor(B0, 32), sB1 = __shfl_xor(B1, 32);
                    const unsigned int sA0 = __shfl_xor(A0, 32), sA1 = __shfl_xor(A1, 32);
                    const unsigned int U0 = hf ? sB0 : A0;
                    const unsigned int U1 = hf ? sB1 : A1;
                    const unsigned int V0 = hf ? B0 : sA0;
                    const unsigned int V1 = hf ? B1 : sA1;
                    const unsigned int xU0 = __shfl_xor(U0, 16), xU1 = __shfl_xor(U1, 16);
                    const unsigned int xV0 = __shfl_xor(V0, 16), xV1 = __shfl_xor(V1, 16);
                    v4u w;
                    w.x = p2 ? xV0 : U0;
                    w.y = p2 ? xV1 : U1;
                    w.z = p2 ? V0 : xU0;
                    w.w = p2 ? V1 : xU1;
                    pfrag[st][s2] = __builtin_bit_cast(v8bf, w);
                }
            }

            // ---- O^T += V^T P^T : mfma(A=vb, B=pfrag) ----
            __builtin_amdgcn_s_setprio(1);
            #pragma unroll
            for (int s2 = 0; s2 < 2; ++s2) {
                if (act0) {
                    #pragma unroll
                    for (int nt = 0; nt < 8; ++nt) {
                        const v8bf vb = *(const v8bf*)&Kb[(24 + nt*2 + s2)*512 + lane*8];
                        O[0][nt] = __builtin_amdgcn_mfma_f32_16x16x32_bf16(vb, pfrag[0][s2], O[0][nt], 0, 0, 0);
                        O[1][nt] = __builtin_amdgcn_mfma_f32_16x16x32_bf16(vb, pfrag[1][s2], O[1][nt], 0, 0, 0);
                    }
                } else {
                    #pragma unroll
                    for (int nt = 0; nt < 8; ++nt) {
                        const v8bf vb = *(const v8bf*)&Kb[(24 + nt*2 + s2)*512 + lane*8];
                        O[1][nt] = __builtin_amdgcn_mfma_f32_16x16x32_bf16(vb, pfrag[1][s2], O[1][nt], 0, 0, 0);
                    }
                }
            }
            __builtin_amdgcn_s_setprio(0);
        }

        // write tile kt+1 into the alt buffer — off the critical path; the
        // next iteration's barrier (implicit vmcnt/lgkmcnt drain) publishes it
        if (kt + 1 < nkt) {
            unsigned short* Kw = KVf[cur ^ 1];
            #pragma unroll
            for (int i = 0; i < 4; ++i)
                *(v8bf*)&Kw[(slot0 + i) * 512 + lane * 8] = R[i];
            *(v8bf*)&Kw[kroff] = R[4];
        }
    }

    // ---- epilogue: O^T per lane holds q = ln-row, vd = nt*16 + quad*4 + r ----
    #pragma unroll
    for (int st = 0; st < 2; ++st) {
        const int qrow = q0 + st*128 + wv*16 + ln;
        const float inv = 1.0f / l_r[st];
        unsigned short* orow =
            (unsigned short*)att + (tokb + qrow) * (size_t)(H_*VDIM_) + h*VDIM_;
        #pragma unroll
        for (int nt = 0; nt < 8; ++nt) {
            #pragma unroll
            for (int rp = 0; rp < 2; ++rp) {
                const unsigned int w =
                    cvt_pk_bf16(O[st][nt][2*rp] * inv, O[st][nt][2*rp+1] * inv);
                *(unsigned int*)(orow + nt*16 + quad*4 + rp*2) = w;
            }
        }
    }
}

// Diagnostic fallback
__global__ void fill_zero(float* p, int n) {
    int i = blockIdx.x * 256 + threadIdx.x;
    if (i < n) p[i] = 0.0f;
}

// ---------------------------------------------------------------------------
extern "C" void kernel_launch(void* const* d_in, const int* in_sizes, int n_in,
                              void* d_out, int out_size, void* d_ws, size_t ws_size,
                              hipStream_t stream)
{
    const float* x      = (const float*)d_in[0];
    const float* wq_w   = (const float*)d_in[1];
    const float* wq_b   = (const float*)d_in[2];
    const float* wkva_w = (const float*)d_in[3];
    const float* wkva_b = (const float*)d_in[4];
    const float* wkvb_w = (const float*)d_in[5];
    const float* wkvb_b = (const float*)d_in[6];
    const float* wo_w   = (const float*)d_in[7];
    const float* wo_b   = (const float*)d_in[8];
    const float* cs     = (const float*)d_in[9];
    const float* sn     = (const float*)d_in[10];

    const size_t q_b    = (size_t)NTOK * 3072 * 2;            // 50,331,648
    const size_t kvf_b  = (size_t)128 * 16 * 32 * 512 * 2;    // 67,108,864
    const size_t xb_b   = (size_t)NTOK * 1024 * 2;
    const size_t kvap_b = (size_t)NTOK * 640 * 2;
    const size_t kvn_b  = (size_t)NTOK * 512 * 2;
    const size_t wq_b_b = (size_t)3072 * 1024 * 2;            // kr aliases this
    const size_t wkva_b_b = (size_t)640 * 1024 * 2;
    const size_t wkvb_b_b = (size_t)4096 * 512 * 2;
    const size_t wo_b_b   = (size_t)1024 * 2048 * 2;
    const size_t bias_b   = 4096;
    const size_t need = q_b + kvf_b + xb_b + kvap_b + kvn_b +
                        wq_b_b + wkva_b_b + wkvb_b_b + wo_b_b + bias_b;

    if (ws_size < need) {
        fill_zero<<<(out_size + 255) / 256, 256, 0, stream>>>((float*)d_out, out_size);
        return;
    }

    char* p = (char*)d_ws;
    __hip_bfloat16* q    = (__hip_bfloat16*)p;             p += q_b;
    unsigned short* kvf  = (unsigned short*)p;             p += kvf_b;
    char*           dynr = p;
    __hip_bfloat16* xb   = (__hip_bfloat16*)p;             p += xb_b;
    __hip_bfloat16* kvap = (__hip_bfloat16*)p;             p += kvap_b;
    __hip_bfloat16* kvn  = (__hip_bfloat16*)p;             p += kvn_b;
    __hip_bfloat16* wq_bf = (__hip_bfloat16*)p;
    __hip_bfloat16* kr    = (__hip_bfloat16*)p;            p += wq_b_b;
    __hip_bfloat16* wkva_bf = (__hip_bfloat16*)p;          p += wkva_b_b;
    __hip_bfloat16* wkvb_bf = (__hip_bfloat16*)p;          p += wkvb_b_b;
    __hip_bfloat16* wo_bf   = (__hip_bfloat16*)p;          p += wo_b_b;
    float*          bias_pad = (float*)p;
    __hip_bfloat16* attb = (__hip_bfloat16*)dynr;
    float*          out  = (float*)d_out;

    // 1) all conversions, one launch
    cvt_all<<<CVT_TOTAL / 256, 256, 0, stream>>>(
        x, wq_w, wkvb_w, wo_w, wkva_w, wkva_b,
        xb, wq_bf, wkvb_bf, wo_bf, wkva_bf, bias_pad);

    // 2) fused q-proj + kva-proj (q-RoPE fused in attn)
    gemm_qkva<<<dim3(29, NTOK/128), 256, 0, stream>>>(
        xb, wq_bf, wq_b, q, wkva_bf, bias_pad, kvap);

    // 3) rmsnorm + rope-k  (kr overwrites wq_bf region — wq_bf dead after step 2)
    rmsnorm_ropek<<<NTOK, 256, 0, stream>>>(kvap, kvn, kr, cs, sn);

    // 4) kv_b -> fragment-ordered kvf (K_nope frags 0..15, V frags 16..31)
    gemm_mfma<__hip_bfloat16, 1><<<dim3(4096/128, NTOK/128), 256, 0, stream>>>(
        kvn, 512, wkvb_bf, 512, wkvb_b, (( __hip_bfloat16*)nullptr), 0, 512, kvf);

    // 5) attention: swapped-QK + double-buffered KVf (1 barrier/K-tile)
    attn_mfma<<<dim3(T_/256, H_, B_), 512, 0, stream>>>(q, kvf, kr, cs, sn, attb);

    // 6) out = att @ wo^T + b  (8192 x 1024, K=2048)
    gemm_mfma<float, 0><<<dim3(1024/128, NTOK/128), 256, 0, stream>>>(
        attb, 2048, wo_bf, 2048, wo_b, out, 1024, 2048, nullptr);
}

// Round 8
// 466.225 us; speedup vs baseline: 1.0298x; 1.0298x over previous
//
#include <hip/hip_runtime.h>
#include <hip/hip_bf16.h>
#include <cmath>
#include <type_traits>

// Problem constants
#define B_    4
#define T_    2048
#define DIM_  1024
#define H_    16
#define NOPE_ 128
#define ROPE_ 64
#define VDIM_ 128
#define KVR_  512
#define QKD_  192          // NOPE + ROPE
#define NTOK  (B_ * T_)    // 8192

static constexpr float SCALE2_ = 0.07216878364870322f * 1.4426950408889634f; // 1/sqrt(192) * log2(e)

typedef __attribute__((ext_vector_type(8))) unsigned short ushort8_t;
typedef __bf16 v8bf __attribute__((ext_vector_type(8)));
typedef float  v4f  __attribute__((ext_vector_type(4)));
typedef unsigned int v4u __attribute__((ext_vector_type(4)));

template <int N> using ic = std::integral_constant<int, N>;

struct PFrag { v8bf a, b; };

__device__ __forceinline__ float bf2f(unsigned short u) {
    return __uint_as_float(((unsigned int)u) << 16);
}
__device__ __forceinline__ unsigned short f2bf(float f) {
    unsigned int u = __float_as_uint(f);
    u += 0x7FFFu + ((u >> 16) & 1u);
    return (unsigned short)(u >> 16);
}
// HW bf16 convert: fptrunc f32->bf16 lowers to v_cvt_pk_bf16_f32 (1 inst, RTNE)
__device__ __forceinline__ unsigned short f2bf_hw(float f) {
    return __builtin_bit_cast(unsigned short, (__bf16)f);
}
// packed pair: low16 = bf16(lo), high16 = bf16(hi) — single instruction
__device__ __forceinline__ unsigned int cvt_pk_bf16(float lo, float hi) {
    unsigned int r;
    asm("v_cvt_pk_bf16_f32 %0, %1, %2" : "=v"(r) : "v"(lo), "v"(hi));
    return r;
}
__device__ __forceinline__ void store1(float* p, float v)          { *p = v; }
__device__ __forceinline__ void store1(__hip_bfloat16* p, float v) { *p = __float2bfloat16(v); }

// RAW v_exp_f32 (D = 2^S0) — 1 instruction (r10 lesson: exp2f is OCML, slow).
__device__ __forceinline__ float exp2_hw(float x) {
    return __builtin_amdgcn_exp2f(x);
}

// async global->LDS, 16B per lane. LDS dest = wave-uniform base + lane*16.
__device__ __forceinline__ void load_lds16(const void* g, void* l) {
    __builtin_amdgcn_global_load_lds(
        (const __attribute__((address_space(1))) void*)g,
        (__attribute__((address_space(3))) void*)l, 16, 0, 0);
}

__device__ __forceinline__ void cvt4(const float* s, __hip_bfloat16* d, int q4) {
    const int i = q4 * 4;
    const float4 v = *(const float4*)(s + i);
    ushort4 o;
    o.x = f2bf(v.x); o.y = f2bf(v.y); o.z = f2bf(v.z); o.w = f2bf(v.w);
    *(ushort4*)((unsigned short*)d + i) = o;
}

// ---------------------------------------------------------------------------
// ONE kernel for all fp32->bf16 conversions.
// ---------------------------------------------------------------------------
#define X4_   (NTOK*1024/4)
#define Q4_   (3072*1024/4)
#define KB4_  (4096*512/4)
#define O4_   (1024*2048/4)
#define A4_   (640*1024/4)
#define CVT_TOTAL (X4_ + Q4_ + KB4_ + O4_ + A4_)

__global__ __launch_bounds__(256) void cvt_all(
    const float* __restrict__ x,    const float* __restrict__ wq,
    const float* __restrict__ wkvb, const float* __restrict__ wo,
    const float* __restrict__ wkva, const float* __restrict__ wkva_bias,
    __hip_bfloat16* __restrict__ xb,    __hip_bfloat16* __restrict__ wqb,
    __hip_bfloat16* __restrict__ wkvbb, __hip_bfloat16* __restrict__ wob,
    __hip_bfloat16* __restrict__ wkvab, float* __restrict__ bias_pad)
{
    int idx = blockIdx.x * 256 + threadIdx.x;
    if (idx < X4_) { cvt4(x, xb, idx); return; }
    idx -= X4_;
    if (idx < Q4_) { cvt4(wq, wqb, idx); return; }
    idx -= Q4_;
    if (idx < KB4_) { cvt4(wkvb, wkvbb, idx); return; }
    idx -= KB4_;
    if (idx < O4_) { cvt4(wo, wob, idx); return; }
    idx -= O4_;
    if (idx < A4_) {
        const int i = idx * 4;
        ushort4 o;
        if (i < 576 * 1024) {
            const float4 v = *(const float4*)(wkva + i);
            o.x = f2bf(v.x); o.y = f2bf(v.y); o.z = f2bf(v.z); o.w = f2bf(v.w);
        } else {
            o.x = o.y = o.z = o.w = 0;
        }
        *(ushort4*)((unsigned short*)wkvab + i) = o;
        if (idx < 640) bias_pad[idx] = (idx < 576) ? wkva_bias[idx] : 0.0f;
    }
}

// ---------------------------------------------------------------------------
// Shared GEMM staging: 128x32 A-tile + 128x32 B-tile via global_load_lds x4.
// ---------------------------------------------------------------------------
__device__ __forceinline__ void gemm_stage(
    const __hip_bfloat16* __restrict__ A, int lda,
    const __hip_bfloat16* __restrict__ W, int ldw,
    int m0, int n0, int k0,
    unsigned short* A_s, unsigned short* B_s, int wv, int ln)
{
    #pragma unroll
    for (int it = 0; it < 2; ++it) {
        const int idx = it * 256 + wv * 64;
        const int li  = idx + ln;
        const int row = li >> 2, ch = li & 3;
        load_lds16(A + (size_t)(m0 + row) * lda + k0 + ch * 8, &A_s[idx * 8]);
        load_lds16(W + (size_t)(n0 + row) * ldw + k0 + ch * 8, &B_s[idx * 8]);
    }
}

// ---------------------------------------------------------------------------
// MFMA GEMM: C[m][n] = sum_k A[m][k]*W[n][k] + bias[n].
// T1 XCD swizzle (kept). T3-minimum 2-phase K-loop: double-buffered 32 KB
// LDS, next-tile global_load_lds ISSUED BEFORE compute, ONE barrier per
// K-step after compute — the barrier's vmcnt(0) drain lands when the
// prefetch is nearly done (hidden under 16 MFMAs).
// EPI=0: plain store.  EPI=1 (kv_b): fragment-ordered kvf via LDS bounce.
// ---------------------------------------------------------------------------
template <typename CT, int EPI>
__global__ __launch_bounds__(256) void gemm_mfma(
    const __hip_bfloat16* __restrict__ A, int lda,
    const __hip_bfloat16* __restrict__ W, int ldw,
    const float* __restrict__ bias,
    CT* __restrict__ C, int ldc, int K,
    unsigned short* __restrict__ kvf)
{
    __shared__ unsigned short smem[2 * 8192];   // 32 KB: 2 x (A|B) buffers

    const int tid  = threadIdx.x;
    const int ln   = tid & 63;
    const int wv   = tid >> 6;
    const int l15  = ln & 15;
    const int quad = ln >> 4;
    const int wm   = wv & 1, wn = wv >> 1;

    // XCD-stripe swizzle (x-major work enumeration)
    const int nwx = (int)gridDim.x, nwy = (int)gridDim.y;
    const int flat = (int)blockIdx.x + nwx * (int)blockIdx.y;
    const int cpx = (nwx * nwy) >> 3;               // nwg % 8 == 0
    const int swz = (flat & 7) * cpx + (flat >> 3);
    const int n0 = (swz / nwy) * 128, m0 = (swz % nwy) * 128;

    v4f acc[4][4] = {};

    gemm_stage(A, lda, W, ldw, m0, n0, 0, smem, smem + 4096, wv, ln);
    __syncthreads();

    int cur = 0;
    for (int k0 = 0; k0 < K; k0 += 32) {
        if (k0 + 32 < K)
            gemm_stage(A, lda, W, ldw, m0, n0, k0 + 32,
                       smem + (cur ^ 1) * 8192, smem + (cur ^ 1) * 8192 + 4096,
                       wv, ln);
        const unsigned short* A_s = smem + cur * 8192;
        const unsigned short* B_s = A_s + 4096;

        v8bf af[4], bf_[4];
        #pragma unroll
        for (int i = 0; i < 4; ++i) {
            af[i]  = *(const v8bf*)&A_s[(wm * 64 + i * 16 + l15) * 32 + quad * 8];
            bf_[i] = *(const v8bf*)&B_s[(wn * 64 + i * 16 + l15) * 32 + quad * 8];
        }
        #pragma unroll
        for (int i = 0; i < 4; ++i)
            #pragma unroll
            for (int j = 0; j < 4; ++j)
                acc[i][j] = __builtin_amdgcn_mfma_f32_16x16x32_bf16(
                                af[i], bf_[j], acc[i][j], 0, 0, 0);
        __syncthreads();
        cur ^= 1;
    }

    if (EPI == 0) {
        #pragma unroll
        for (int i = 0; i < 4; ++i) {
            const int mrow = m0 + wm * 64 + i * 16 + quad * 4;
            #pragma unroll
            for (int j = 0; j < 4; ++j) {
                const int ncol = n0 + wn * 64 + j * 16 + l15;
                const float bb = bias[ncol];
                #pragma unroll
                for (int r = 0; r < 4; ++r)
                    store1(C + (size_t)(mrow + r) * ldc + ncol, acc[i][j][r] + bb);
            }
        }
    } else {
        const int head = n0 >> 8;
        const bool is_v = (n0 & 128) != 0;
        #pragma unroll
        for (int p = 0; p < 2; ++p) {          // p = local ktile = wm
            if (p) __syncthreads();            // pass-0 copyout done
            if (wm == p) {
                #pragma unroll
                for (int i = 0; i < 4; ++i) {
                    #pragma unroll
                    for (int j = 0; j < 4; ++j) {
                        const int ncl = wn * 64 + j * 16 + l15;   // dim 0..127
                        const float bb = bias[n0 + ncl];
                        #pragma unroll
                        for (int r = 0; r < 4; ++r) {
                            const unsigned short v = f2bf(acc[i][j][r] + bb);
                            const int lnf = quad * 4 + r;          // tok%16
                            int off;
                            if (!is_v) {
                                const int s = ncl >> 5, qf = (ncl >> 3) & 3, e = ncl & 7;
                                off = (s * 4 + i) * 512 + (qf * 16 + lnf) * 8 + e;
                            } else {
                                const int nt = ncl >> 4, lnv = ncl & 15;
                                const int jj = i * 16 + lnf;       // tok%64
                                const int s2 = jj >> 5, qv = (jj >> 3) & 3, ev = jj & 7;
                                off = (nt * 2 + s2) * 512 + (qv * 16 + lnv) * 8 + ev;
                            }
                            smem[off] = v;
                        }
                    }
                }
            }
            __syncthreads();
            // coalesced copy: 16 KB fragment block -> kvf
            const size_t GT = (size_t)(m0 >> 6) + p;
            unsigned short* dst = kvf + ((GT * 16 + head) << 14) + (is_v ? 16 * 512 : 0);
            #pragma unroll
            for (int it = 0; it < 4; ++it) {
                const int u = (tid + it * 256) * 8;
                *(ushort8_t*)(dst + u) = *(const ushort8_t*)&smem[u];
            }
        }
    }
}

// ---------------------------------------------------------------------------
// Fused q-proj + kva-proj (same A operand, K=1024): one launch, branch on bx.
// Same T1 XCD swizzle + T3-minimum 2-phase K-loop.
// ---------------------------------------------------------------------------
__global__ __launch_bounds__(256) void gemm_qkva(
    const __hip_bfloat16* __restrict__ A,
    const __hip_bfloat16* __restrict__ Wq, const float* __restrict__ biasq,
    __hip_bfloat16* __restrict__ Cq,
    const __hip_bfloat16* __restrict__ Wa, const float* __restrict__ biasa,
    __hip_bfloat16* __restrict__ Ca)
{
    __shared__ unsigned short smem[2 * 8192];   // 32 KB

    const int flat = (int)blockIdx.x + 29 * (int)blockIdx.y;
    const int swz  = (flat & 7) * (1856 >> 3) + (flat >> 3);
    const int xw   = swz / 64, yw = swz % 64;

    const bool is_q = xw < 24;
    const __hip_bfloat16* W = is_q ? Wq : Wa;
    const float* bias       = is_q ? biasq : biasa;
    __hip_bfloat16* C       = is_q ? Cq : Ca;
    const int ldc = is_q ? 3072 : 640;
    const int n0  = (is_q ? xw : (xw - 24)) * 128;
    const int m0  = yw * 128;

    const int tid  = threadIdx.x;
    const int ln   = tid & 63;
    const int wv   = tid >> 6;
    const int l15  = ln & 15;
    const int quad = ln >> 4;
    const int wm   = wv & 1, wn = wv >> 1;

    v4f acc[4][4] = {};

    gemm_stage(A, 1024, W, 1024, m0, n0, 0, smem, smem + 4096, wv, ln);
    __syncthreads();

    int cur = 0;
    for (int k0 = 0; k0 < 1024; k0 += 32) {
        if (k0 + 32 < 1024)
            gemm_stage(A, 1024, W, 1024, m0, n0, k0 + 32,
                       smem + (cur ^ 1) * 8192, smem + (cur ^ 1) * 8192 + 4096,
                       wv, ln);
        const unsigned short* A_s = smem + cur * 8192;
        const unsigned short* B_s = A_s + 4096;

        v8bf af[4], bf_[4];
        #pragma unroll
        for (int i = 0; i < 4; ++i) {
            af[i]  = *(const v8bf*)&A_s[(wm * 64 + i * 16 + l15) * 32 + quad * 8];
            bf_[i] = *(const v8bf*)&B_s[(wn * 64 + i * 16 + l15) * 32 + quad * 8];
        }
        #pragma unroll
        for (int i = 0; i < 4; ++i)
            #pragma unroll
            for (int j = 0; j < 4; ++j)
                acc[i][j] = __builtin_amdgcn_mfma_f32_16x16x32_bf16(
                                af[i], bf_[j], acc[i][j], 0, 0, 0);
        __syncthreads();
        cur ^= 1;
    }

    #pragma unroll
    for (int i = 0; i < 4; ++i) {
        const int mrow = m0 + wm * 64 + i * 16 + quad * 4;
        #pragma unroll
        for (int j = 0; j < 4; ++j) {
            const int ncol = n0 + wn * 64 + j * 16 + l15;
            const float bb = bias[ncol];
            #pragma unroll
            for (int r = 0; r < 4; ++r)
                C[(size_t)(mrow + r) * ldc + ncol] = __float2bfloat16(acc[i][j][r] + bb);
        }
    }
}

// ---------------------------------------------------------------------------
// RMS-norm kv_a[:,0:512] -> kvn bf16; RoPE kv_a[:,512:576] -> kr bf16.
// ---------------------------------------------------------------------------
__global__ __launch_bounds__(256) void rmsnorm_ropek(
    const __hip_bfloat16* __restrict__ kva,
    __hip_bfloat16* __restrict__ kvn,
    __hip_bfloat16* __restrict__ kr,
    const float* __restrict__ cs,
    const float* __restrict__ sn)
{
    const int tok = blockIdx.x;
    const int tid = threadIdx.x;
    const __hip_bfloat16* row = kva + (size_t)tok * 640;

    const float x0 = __bfloat162float(row[tid]);
    const float x1 = __bfloat162float(row[tid + 256]);
    float ss = x0*x0 + x1*x1;
    #pragma unroll
    for (int off = 32; off >= 1; off >>= 1)
        ss += __shfl_down(ss, off);

    __shared__ float red[4];
    __shared__ float scale_sh;
    if ((tid & 63) == 0) red[tid >> 6] = ss;
    __syncthreads();
    if (tid == 0) {
        const float tot = red[0] + red[1] + red[2] + red[3];
        scale_sh = rsqrtf(tot * (1.0f/512.0f) + 1e-6f);
    }
    __syncthreads();
    const float sc = scale_sh;
    kvn[(size_t)tok*512 + tid]       = __float2bfloat16(x0 * sc);
    kvn[(size_t)tok*512 + tid + 256] = __float2bfloat16(x1 * sc);

    if (tid < 32) {
        const int t = tok & (T_ - 1);
        const float c = cs[t*32 + tid];
        const float s = sn[t*32 + tid];
        const float xr = __bfloat162float(row[KVR_ + 2*tid]);
        const float xi = __bfloat162float(row[KVR_ + 2*tid + 1]);
        kr[(size_t)tok*64 + 2*tid]     = __float2bfloat16(xr * c - xi * s);
        kr[(size_t)tok*64 + 2*tid + 1] = __float2bfloat16(xr * s + xi * c);
    }
}

// ---------------------------------------------------------------------------
// MFMA flash attention, BQ=256 / BK=64, 8 waves, two q-strips per wave.
// SWAPPED QK^T + lane-local softmax + in-register P frags + KVf dbuf.
//
// Per-iter PHASE INTERLEAVE (this round): old order QK->SM1->SM0->PV(both)
// bunched all waves into MFMA-only then VALU-only phases. New order:
//   QK(both, shared K reads) -> SM1 -> PV1 -> SM0 -> PV0
// PV1's 16 MFMAs and SM0's VALU are independent and share a scheduling
// region -> compiler interleaves them. Cost: PV strips no longer share vb
// reads (+16 ds_read/iter) — cheap vs the stall.
// ---------------------------------------------------------------------------
__device__ __forceinline__ void attn_stage_regs(
    v8bf* R,
    const unsigned short* __restrict__ kvf,
    const __hip_bfloat16* __restrict__ kr,
    size_t tokb, int j0, int h, int wv, int lane, int tid)
{
    const size_t GT = (tokb + j0) >> 6;
    const unsigned short* base = kvf + ((GT * 16 + h) << 14);
    #pragma unroll
    for (int i = 0; i < 4; ++i)
        R[i] = *(const v8bf*)(base + ((wv * 4 + i) << 9) + lane * 8);
    // kr: thread (j=tid>>3, dch=tid&7) -> 16B coalesced
    const int j = tid >> 3, dch = tid & 7;
    R[4] = *(const v8bf*)((const unsigned short*)kr + (tokb + j0 + j) * 64 + dch * 8);
}

__global__ __launch_bounds__(512, 2) void attn_mfma(
    const __hip_bfloat16* __restrict__ q,
    const unsigned short* __restrict__ kvf,
    const __hip_bfloat16* __restrict__ kr,
    const float* __restrict__ cs,
    const float* __restrict__ sn,
    __hip_bfloat16* __restrict__ att)
{
    __shared__ unsigned short KVf[2][40 * 512];     // 80 KB, double-buffered

    const int tid  = threadIdx.x;
    const int lane = tid & 63;
    const int ln   = tid & 15;
    const int quad = (tid >> 4) & 3;
    const int wv   = tid >> 6;                      // 0..7
    const int hf   = quad >> 1;                     // 1 iff lane >= 32
    const int p2   = quad & 1;

    // ---- balanced (qt,h,b) mapping from flattened dispatch id ----
    const int bid  = (int)(blockIdx.x + 8u * blockIdx.y + 128u * blockIdx.z);
    const int half = bid >> 8;          // 0 or 1
    const int id2  = bid & 255;
    const int pr   = id2 & 3;           // complementary pair id (0..3)
    const int h    = (id2 >> 2) & 15;
    const int b    = id2 >> 6;
    const int qt   = half ? pr : (7 - pr);

    const int q0 = qt * 256;
    const size_t tokb = (size_t)b * T_;

    // ---- Q fragments (B operand), fused RoPE + base2 scale ----
    v8bf qf[2][6];
    #pragma unroll
    for (int st = 0; st < 2; ++st) {
        const int trow = q0 + st*128 + wv*16 + ln;
        const __hip_bfloat16* qrow =
            q + (tokb + trow) * (size_t)(H_*QKD_) + h*QKD_;
        #pragma unroll
        for (int s = 0; s < 6; ++s) {
            ushort8_t raw = *(const ushort8_t*)(qrow + s*32 + quad*8);
            ushort8_t o;
            if (s < 4) {
                #pragma unroll
                for (int i = 0; i < 8; ++i)
                    o[i] = f2bf_hw(bf2f(raw[i]) * SCALE2_);
            } else {
                #pragma unroll
                for (int pp2 = 0; pp2 < 4; ++pp2) {
                    const int fi = (s-4)*16 + quad*4 + pp2;
                    const float c  = cs[trow*32 + fi];
                    const float sv = sn[trow*32 + fi];
                    const float xr = bf2f(raw[pp2*2]);
                    const float xi = bf2f(raw[pp2*2+1]);
                    o[pp2*2]   = f2bf_hw((xr*c - xi*sv) * SCALE2_);
                    o[pp2*2+1] = f2bf_hw((xr*sv + xi*c) * SCALE2_);
                }
            }
            qf[st][s] = __builtin_bit_cast(v8bf, o);
        }
    }

    v4f O[2][8];
    #pragma unroll
    for (int st = 0; st < 2; ++st)
        #pragma unroll
        for (int nt = 0; nt < 8; ++nt) O[st][nt] = (v4f){0.f, 0.f, 0.f, 0.f};
    float m_r[2] = {-1e30f, -1e30f};
    float l_r[2] = {0.0f, 0.0f};

    const int qmin0 = q0 + wv*16;
    const int qmin1 = q0 + 128 + wv*16;
    const int nkt = (q0 + 256) >> 6;

    // LDS slot base for this wave's 4 kvf fragments (kn->0..15, V->24..39)
    const int slot0 = (wv < 4) ? (wv * 4) : (wv * 4 + 8);
    // kr LDS target for this thread
    const int krj = tid >> 3, krd = tid & 7;
    const int krfrag = 16 + (krd >> 2) * 4 + (krj >> 4);
    const int kroff  = krfrag * 512 + ((krd & 3) * 16 + (krj & 15)) * 8;

    // prefetch tile 0 and write it into buffer 0 (pre-loop)
    v8bf R[5];
    attn_stage_regs(R, kvf, kr, tokb, 0, h, wv, lane, tid);
    {
        unsigned short* Kw = KVf[0];
        #pragma unroll
        for (int i = 0; i < 4; ++i)
            *(v8bf*)&Kw[(slot0 + i) * 512 + lane * 8] = R[i];
        *(v8bf*)&Kw[kroff] = R[4];
    }

    for (int kt = 0; kt < nkt; ++kt) {
        const int j0 = kt << 6;
        const int cur = kt & 1;
        const unsigned short* Kb = KVf[cur];

        __syncthreads();   // buf[cur] visible; buf[cur^1] free (readers done)

        if (kt + 1 < nkt)
            attn_stage_regs(R, kvf, kr, tokb, j0 + 64, h, wv, lane, tid);

        const bool act0 = (j0 <= qmin0 + 15);   // wave-uniform
        const bool act1 = (j0 <= qmin1 + 15);

        if (act1) {
            v4f S[2][4];
            #pragma unroll
            for (int st = 0; st < 2; ++st)
                #pragma unroll
                for (int t = 0; t < 4; ++t) S[st][t] = (v4f){0.f, 0.f, 0.f, 0.f};

            // ---- lane-local online softmax + P fragment build for strip ST ----
            auto SM = [&](auto STc) -> PFrag {
                constexpr int ST = STc.value;
                const int qmin = (ST == 0) ? qmin0 : qmin1;
                const int qrow = qmin + ln;
                if (j0 + 63 > qmin) {
                    #pragma unroll
                    for (int t = 0; t < 4; ++t) {
                        const int kbase = j0 + t*16 + quad*4;
                        #pragma unroll
                        for (int r = 0; r < 4; ++r)
                            if (kbase + r > qrow) S[ST][t][r] = -1e30f;
                    }
                }
                // row max: balanced lane-local tree + 2 cross-quad shfls
                float m0_ = fmaxf(fmaxf(S[ST][0][0], S[ST][0][1]),
                                  fmaxf(S[ST][0][2], S[ST][0][3]));
                float m1_ = fmaxf(fmaxf(S[ST][1][0], S[ST][1][1]),
                                  fmaxf(S[ST][1][2], S[ST][1][3]));
                float m2_ = fmaxf(fmaxf(S[ST][2][0], S[ST][2][1]),
                                  fmaxf(S[ST][2][2], S[ST][2][3]));
                float m3_ = fmaxf(fmaxf(S[ST][3][0], S[ST][3][1]),
                                  fmaxf(S[ST][3][2], S[ST][3][3]));
                float mx = fmaxf(fmaxf(m0_, m1_), fmaxf(m2_, m3_));
                mx = fmaxf(mx, __shfl_xor(mx, 16));
                mx = fmaxf(mx, __shfl_xor(mx, 32));
                const bool need = mx > m_r[ST] + 8.0f;  // defer-max THR=8 (base-2)
                if (__any((int)need)) {
                    const float mn = fmaxf(m_r[ST], mx);
                    const float alpha = exp2_hw(m_r[ST] - mn);
                    m_r[ST] = mn;
                    l_r[ST] *= alpha;
                    #pragma unroll
                    for (int nt = 0; nt < 8; ++nt)
                        O[ST][nt] *= alpha;
                }
                // exp + lane-local sum + 2 shfls
                float rs = 0.0f;
                #pragma unroll
                for (int t = 0; t < 4; ++t)
                    #pragma unroll
                    for (int r = 0; r < 4; ++r) {
                        const float pp = exp2_hw(S[ST][t][r] - m_r[ST]);
                        S[ST][t][r] = pp;
                        rs += pp;
                    }
                rs += __shfl_xor(rs, 16);
                rs += __shfl_xor(rs, 32);
                l_r[ST] += rs;
                // pack P pairs + quad exchange -> B fragments
                unsigned int pk[4][2];
                #pragma unroll
                for (int t = 0; t < 4; ++t)
                    #pragma unroll
                    for (int i = 0; i < 2; ++i)
                        pk[t][i] = cvt_pk_bf16(S[ST][t][2*i], S[ST][t][2*i+1]);
                PFrag out;
                #pragma unroll
                for (int s2 = 0; s2 < 2; ++s2) {
                    const unsigned int A0 = pk[2*s2][0],   A1 = pk[2*s2][1];
                    const unsigned int B0 = pk[2*s2+1][0], B1 = pk[2*s2+1][1];
                    const unsigned int sB0 = __shfl_xor(B0, 32), sB1 = __shfl_xor(B1, 32);
                    const unsigned int sA0 = __shfl_xor(A0, 32), sA1 = __shfl_xor(A1, 32);
                    const unsigned int U0 = hf ? sB0 : A0;
                    const unsigned int U1 = hf ? sB1 : A1;
                    const unsigned int V0 = hf ? B0 : sA0;
                    const unsigned int V1 = hf ? B1 : sA1;
                    const unsigned int xU0 = __shfl_xor(U0, 16), xU1 = __shfl_xor(U1, 16);
                    const unsigned int xV0 = __shfl_xor(V0, 16), xV1 = __shfl_xor(V1, 16);
                    v4u w;
                    w.x = p2 ? xV0 : U0;
                    w.y = p2 ? xV1 : U1;
                    w.z = p2 ? V0 : xU0;
                    w.w = p2 ? V1 : xU1;
                    if (s2 == 0) out.a = __builtin_bit_cast(v8bf, w);
                    else         out.b = __builtin_bit_cast(v8bf, w);
                }
                return out;
            };

            // ---- PV for strip ST ----
            auto PV = [&](auto STc, v8bf pf0, v8bf pf1) {
                constexpr int ST = STc.value;
                __builtin_amdgcn_s_setprio(1);
                #pragma unroll
                for (int s2 = 0; s2 < 2; ++s2) {
                    const v8bf pfx = s2 ? pf1 : pf0;
                    #pragma unroll
                    for (int nt = 0; nt < 8; ++nt) {
                        const v8bf vb = *(const v8bf*)&Kb[(24 + nt*2 + s2)*512 + lane*8];
                        O[ST][nt] = __builtin_amdgcn_mfma_f32_16x16x32_bf16(
                                        vb, pfx, O[ST][nt], 0, 0, 0);
                    }
                }
                __builtin_amdgcn_s_setprio(0);
            };

            // ---- S^T = K Q^T (shared kb reads, both strips interleaved) ----
            __builtin_amdgcn_s_setprio(1);
            if (act0) {
                #pragma unroll
                for (int s = 0; s < 6; ++s)
                    #pragma unroll
                    for (int t = 0; t < 4; ++t) {
                        const v8bf kb = *(const v8bf*)&Kb[(s*4 + t)*512 + lane*8];
                        S[1][t] = __builtin_amdgcn_mfma_f32_16x16x32_bf16(kb, qf[1][s], S[1][t], 0, 0, 0);
                        S[0][t] = __builtin_amdgcn_mfma_f32_16x16x32_bf16(kb, qf[0][s], S[0][t], 0, 0, 0);
                    }
            } else {
                #pragma unroll
                for (int s = 0; s < 6; ++s)
                    #pragma unroll
                    for (int t = 0; t < 4; ++t) {
                        const v8bf kb = *(const v8bf*)&Kb[(s*4 + t)*512 + lane*8];
                        S[1][t] = __builtin_amdgcn_mfma_f32_16x16x32_bf16(kb, qf[1][s], S[1][t], 0, 0, 0);
                    }
            }
            __builtin_amdgcn_s_setprio(0);

            // ---- interleaved phases: SM1 -> PV1 -> SM0 -> PV0 ----
            if (act0) {
                PFrag p1 = SM(ic<1>{});
                PV(ic<1>{}, p1.a, p1.b);      // PV1 MFMAs interleave w/ SM0 VALU
                PFrag p0 = SM(ic<0>{});
                PV(ic<0>{}, p0.a, p0.b);
            } else {
                PFrag p1 = SM(ic<1>{});
                PV(ic<1>{}, p1.a, p1.b);
            }
        }

        // write tile kt+1 into the alt buffer — off the critical path
        if (kt + 1 < nkt) {
            unsigned short* Kw = KVf[cur ^ 1];
            #pragma unroll
            for (int i = 0; i < 4; ++i)
                *(v8bf*)&Kw[(slot0 + i) * 512 + lane * 8] = R[i];
            *(v8bf*)&Kw[kroff] = R[4];
        }
    }

    // ---- epilogue: O^T per lane holds q = ln-row, vd = nt*16 + quad*4 + r ----
    #pragma unroll
    for (int st = 0; st < 2; ++st) {
        const int qrow = q0 + st*128 + wv*16 + ln;
        const float inv = 1.0f / l_r[st];
        unsigned short* orow =
            (unsigned short*)att + (tokb + qrow) * (size_t)(H_*VDIM_) + h*VDIM_;
        #pragma unroll
        for (int nt = 0; nt < 8; ++nt) {
            #pragma unroll
            for (int rp = 0; rp < 2; ++rp) {
                const unsigned int w =
                    cvt_pk_bf16(O[st][nt][2*rp] * inv, O[st][nt][2*rp+1] * inv);
                *(unsigned int*)(orow + nt*16 + quad*4 + rp*2) = w;
            }
        }
    }
}

// Diagnostic fallback
__global__ void fill_zero(float* p, int n) {
    int i = blockIdx.x * 256 + threadIdx.x;
    if (i < n) p[i] = 0.0f;
}

// ---------------------------------------------------------------------------
extern "C" void kernel_launch(void* const* d_in, const int* in_sizes, int n_in,
                              void* d_out, int out_size, void* d_ws, size_t ws_size,
                              hipStream_t stream)
{
    const float* x      = (const float*)d_in[0];
    const float* wq_w   = (const float*)d_in[1];
    const float* wq_b   = (const float*)d_in[2];
    const float* wkva_w = (const float*)d_in[3];
    const float* wkva_b = (const float*)d_in[4];
    const float* wkvb_w = (const float*)d_in[5];
    const float* wkvb_b = (const float*)d_in[6];
    const float* wo_w   = (const float*)d_in[7];
    const float* wo_b   = (const float*)d_in[8];
    const float* cs     = (const float*)d_in[9];
    const float* sn     = (const float*)d_in[10];

    const size_t q_b    = (size_t)NTOK * 3072 * 2;            // 50,331,648
    const size_t kvf_b  = (size_t)128 * 16 * 32 * 512 * 2;    // 67,108,864
    const size_t xb_b   = (size_t)NTOK * 1024 * 2;
    const size_t kvap_b = (size_t)NTOK * 640 * 2;
    const size_t kvn_b  = (size_t)NTOK * 512 * 2;
    const size_t wq_b_b = (size_t)3072 * 1024 * 2;            // kr aliases this
    const size_t wkva_b_b = (size_t)640 * 1024 * 2;
    const size_t wkvb_b_b = (size_t)4096 * 512 * 2;
    const size_t wo_b_b   = (size_t)1024 * 2048 * 2;
    const size_t bias_b   = 4096;
    const size_t need = q_b + kvf_b + xb_b + kvap_b + kvn_b +
                        wq_b_b + wkva_b_b + wkvb_b_b + wo_b_b + bias_b;

    if (ws_size < need) {
        fill_zero<<<(out_size + 255) / 256, 256, 0, stream>>>((float*)d_out, out_size);
        return;
    }

    char* p = (char*)d_ws;
    __hip_bfloat16* q    = (__hip_bfloat16*)p;             p += q_b;
    unsigned short* kvf  = (unsigned short*)p;             p += kvf_b;
    char*           dynr = p;
    __hip_bfloat16* xb   = (__hip_bfloat16*)p;             p += xb_b;
    __hip_bfloat16* kvap = (__hip_bfloat16*)p;             p += kvap_b;
    __hip_bfloat16* kvn  = (__hip_bfloat16*)p;             p += kvn_b;
    __hip_bfloat16* wq_bf = (__hip_bfloat16*)p;
    __hip_bfloat16* kr    = (__hip_bfloat16*)p;            p += wq_b_b;
    __hip_bfloat16* wkva_bf = (__hip_bfloat16*)p;          p += wkva_b_b;
    __hip_bfloat16* wkvb_bf = (__hip_bfloat16*)p;          p += wkvb_b_b;
    __hip_bfloat16* wo_bf   = (__hip_bfloat16*)p;          p += wo_b_b;
    float*          bias_pad = (float*)p;
    __hip_bfloat16* attb = (__hip_bfloat16*)dynr;
    float*          out  = (float*)d_out;

    // 1) all conversions, one launch
    cvt_all<<<CVT_TOTAL / 256, 256, 0, stream>>>(
        x, wq_w, wkvb_w, wo_w, wkva_w, wkva_b,
        xb, wq_bf, wkvb_bf, wo_bf, wkva_bf, bias_pad);

    // 2) fused q-proj + kva-proj (q-RoPE fused in attn)
    gemm_qkva<<<dim3(29, NTOK/128), 256, 0, stream>>>(
        xb, wq_bf, wq_b, q, wkva_bf, bias_pad, kvap);

    // 3) rmsnorm + rope-k  (kr overwrites wq_bf region — wq_bf dead after step 2)
    rmsnorm_ropek<<<NTOK, 256, 0, stream>>>(kvap, kvn, kr, cs, sn);

    // 4) kv_b -> fragment-ordered kvf (K_nope frags 0..15, V frags 16..31)
    gemm_mfma<__hip_bfloat16, 1><<<dim3(4096/128, NTOK/128), 256, 0, stream>>>(
        kvn, 512, wkvb_bf, 512, wkvb_b, (( __hip_bfloat16*)nullptr), 0, 512, kvf);

    // 5) attention: swapped-QK + dbuf + SM/PV phase interleave
    attn_mfma<<<dim3(T_/256, H_, B_), 512, 0, stream>>>(q, kvf, kr, cs, sn, attb);

    // 6) out = att @ wo^T + b  (8192 x 1024, K=2048)
    gemm_mfma<float, 0><<<dim3(1024/128, NTOK/128), 256, 0, stream>>>(
        attb, 2048, wo_bf, 2048, wo_b, out, 1024, 2048, nullptr);
}